// Round 3
// baseline (195.935 us; speedup 1.0000x reference)
//
#include <hip/hip_runtime.h>

typedef float  f32x2  __attribute__((ext_vector_type(2)));
typedef float  f32x4  __attribute__((ext_vector_type(4)));
typedef float  f32x16 __attribute__((ext_vector_type(16)));
typedef short  s16x4  __attribute__((ext_vector_type(4)));
typedef short  s16x8  __attribute__((ext_vector_type(8)));
typedef unsigned int u32x2 __attribute__((ext_vector_type(2)));

__device__ __forceinline__ unsigned f2bf(float f) {
    unsigned u = __builtin_bit_cast(unsigned, f);
    u += 0x7FFFu + ((u >> 16) & 1u);   // RNE
    return u >> 16;
}
__device__ __forceinline__ s16x4 pack4(float a, float b, float c, float d) {
    u32x2 u;
    u[0] = f2bf(a) | (f2bf(b) << 16);
    u[1] = f2bf(c) | (f2bf(d) << 16);
    return __builtin_bit_cast(s16x4, u);
}
__device__ __forceinline__ s16x4 pack4v(f32x4 v) { return pack4(v[0], v[1], v[2], v[3]); }
__device__ __forceinline__ s16x4 lo4(s16x8 v) { return __builtin_shufflevector(v, v, 0, 1, 2, 3); }
__device__ __forceinline__ s16x4 hi4(s16x8 v) { return __builtin_shufflevector(v, v, 4, 5, 6, 7); }

// ---------------------------------------------------------------------------
// Node MLP body (one wave per 32-node tile), proven in R2.
// P = relu(relu(X W1^T + b1) W2^T + b2) Wm^T (+ bm), bf16 out. Wm stride 96.
// ---------------------------------------------------------------------------
__device__ __forceinline__ void node_body(
    const float* __restrict__ X,
    const float* __restrict__ W1, const float* __restrict__ b1,
    const float* __restrict__ W2, const float* __restrict__ b2,
    const float* __restrict__ Wm, const float* __restrict__ bm,
    unsigned short* __restrict__ outp, int N, int tile)
{
    const int lane = threadIdx.x & 63;
    const int g = lane >> 5, m = lane & 31;
    const int ntile = (N + 31) >> 5;
    if (tile >= ntile) return;

    s16x4 a1[4], a2[4], am[4];
#pragma unroll
    for (int q = 0; q < 4; ++q) {
        const float* p1 = W1 + m * 32 + 8 * q + 4 * g;
        a1[q] = pack4(p1[0], p1[1], p1[2], p1[3]);
        const float* p2 = W2 + m * 32 + 8 * q + 4 * g;
        a2[q] = pack4(p2[0], p2[1], p2[2], p2[3]);
        const float* pm = Wm + m * 96 + 8 * q + 4 * g;
        am[q] = pack4(pm[0], pm[1], pm[2], pm[3]);
    }
    f32x16 f1, f2, f3;
#pragma unroll
    for (int r = 0; r < 16; ++r) {
        int ch = (r & 3) + 8 * (r >> 2) + 4 * g;
        f1[r] = b1[ch];
        f2[r] = b2[ch];
        f3[r] = bm ? bm[ch] : 0.f;
    }

    const int node0 = tile * 32 + m;
    const int node = node0 < N ? node0 : N - 1;

    s16x4 bX[4];
#pragma unroll
    for (int q = 0; q < 4; ++q) {
        f32x4 v = *reinterpret_cast<const f32x4*>(X + (size_t)node * 32 + 8 * q + 4 * g);
        bX[q] = pack4v(v);
    }
    f32x16 acc = f1;
#pragma unroll
    for (int q = 0; q < 4; ++q) acc = __builtin_amdgcn_mfma_f32_32x32x8bf16_1k(a1[q], bX[q], acc, 0, 0, 0);
    s16x4 bH[4];
#pragma unroll
    for (int q = 0; q < 4; ++q)
        bH[q] = pack4(fmaxf(acc[4*q+0], 0.f), fmaxf(acc[4*q+1], 0.f),
                      fmaxf(acc[4*q+2], 0.f), fmaxf(acc[4*q+3], 0.f));
    acc = f2;
#pragma unroll
    for (int q = 0; q < 4; ++q) acc = __builtin_amdgcn_mfma_f32_32x32x8bf16_1k(a2[q], bH[q], acc, 0, 0, 0);
#pragma unroll
    for (int q = 0; q < 4; ++q)
        bH[q] = pack4(fmaxf(acc[4*q+0], 0.f), fmaxf(acc[4*q+1], 0.f),
                      fmaxf(acc[4*q+2], 0.f), fmaxf(acc[4*q+3], 0.f));
    acc = f3;
#pragma unroll
    for (int q = 0; q < 4; ++q) acc = __builtin_amdgcn_mfma_f32_32x32x8bf16_1k(am[q], bH[q], acc, 0, 0, 0);

    if (node0 < N) {
#pragma unroll
        for (int q = 0; q < 4; ++q) {
            s16x4 o = pack4(acc[4*q+0], acc[4*q+1], acc[4*q+2], acc[4*q+3]);
            *reinterpret_cast<s16x4*>(outp + (size_t)node0 * 32 + 8 * q + 4 * g) = o;
        }
    }
}

__global__ __launch_bounds__(256) void nodes_kernel(
    const float* __restrict__ var_f, const float* __restrict__ con_f,
    const float* __restrict__ Wv1, const float* __restrict__ bv1,
    const float* __restrict__ Wv2, const float* __restrict__ bv2,
    const float* __restrict__ Wc1, const float* __restrict__ bc1,
    const float* __restrict__ Wc2, const float* __restrict__ bc2,
    const float* __restrict__ We1, const float* __restrict__ be1,
    unsigned short* __restrict__ pv, unsigned short* __restrict__ pc,
    int nV, int nC, int blocksV)
{
    const int wv = threadIdx.x >> 6;
    if ((int)blockIdx.x < blocksV) {
        node_body(var_f, Wv1, bv1, Wv2, bv2, We1 + 32, be1, pv, nV, blockIdx.x * 4 + wv);
    } else {
        node_body(con_f, Wc1, bc1, Wc2, bc2, We1 + 64, nullptr, pc, nC,
                  (blockIdx.x - blocksV) * 4 + wv);
    }
}

// ---------------------------------------------------------------------------
// Edge kernel: fully wave-independent, NO barriers. One wave per 32-edge tile,
// grid-stride. Ef reg-prefetched one tile ahead (per-lane contiguous 64 B via
// the ch=16g+4q+j K-remap); gathers issued at iteration top with idx
// prefetched one ahead; stores transposed through wave-private padded LDS.
// Non-temporal on streaming Ef/idx/out to preserve L2 for pv/pc gathers.
// ---------------------------------------------------------------------------
__global__ __launch_bounds__(256, 4) void edge_kernel(
    const float* __restrict__ Ef, const int* __restrict__ idx,
    const unsigned short* __restrict__ pv, const unsigned short* __restrict__ pc,
    const float* __restrict__ We1, const float* __restrict__ We2,
    const float* __restrict__ be2,
    float* __restrict__ out, int nE)
{
    __shared__ float ldso[4 * 1088];          // 4 waves * 32 rows * stride 34
    const int lane = threadIdx.x & 63;
    const int wv = threadIdx.x >> 6;
    const int g = lane >> 5, n = lane & 31;
    float* ldsw = ldso + wv * 1088;

    // A fragments. Layer 1: ch1(q,g,j)=16g+4q+j; layer 2: ch2=8q+4g+j.
    s16x4 aW1[4], aI[4], aW2[4];
#pragma unroll
    for (int q = 0; q < 4; ++q) {
        const float* p = We1 + n * 96 + 16 * g + 4 * q;
        aW1[q] = pack4(p[0], p[1], p[2], p[3]);
        s16x4 r;
#pragma unroll
        for (int j = 0; j < 4; ++j) r[j] = (short)((16 * g + 4 * q + j == n) ? 0x3F80 : 0);
        aI[q] = r;
        const float* p2 = We2 + n * 32 + 8 * q + 4 * g;
        aW2[q] = pack4(p2[0], p2[1], p2[2], p2[3]);
    }
    // be2 as one extra MFMA: A[:,0]=be2, B[0,:]=1
    s16x4 aB2 = {}, bOne = {};
    if (g == 0) {
        aB2[0] = (short)f2bf(be2[n]);
        bOne[0] = (short)0x3F80;
    }

    const int ntile = nE >> 5;
    const int nw = (gridDim.x * blockDim.x) >> 6;
    int t = (blockIdx.x * blockDim.x + threadIdx.x) >> 6;
    if (t >= ntile) return;

    // ---- prologue: idx(t) and Ef(t) prefetch ----
    int e = t * 32 + n;
    int i0c = __builtin_nontemporal_load(idx + e);
    int i1c = __builtin_nontemporal_load(idx + nE + e);
    const float* efp = Ef + (size_t)e * 32 + 16 * g;
    f32x4 ef0 = __builtin_nontemporal_load(reinterpret_cast<const f32x4*>(efp + 0));
    f32x4 ef1 = __builtin_nontemporal_load(reinterpret_cast<const f32x4*>(efp + 4));
    f32x4 ef2 = __builtin_nontemporal_load(reinterpret_cast<const f32x4*>(efp + 8));
    f32x4 ef3 = __builtin_nontemporal_load(reinterpret_cast<const f32x4*>(efp + 12));

    while (true) {
        const int tn = t + nw;
        const int tc = tn < ntile ? tn : t;    // clamped (loads harmless when done)

        // gathers for current tile (idx already resident)
        const unsigned short* pvr = pv + (size_t)i0c * 32 + 16 * g;
        const unsigned short* pcr = pc + (size_t)i1c * 32 + 16 * g;
        s16x8 gv0 = *reinterpret_cast<const s16x8*>(pvr);
        s16x8 gv1 = *reinterpret_cast<const s16x8*>(pvr + 8);
        s16x8 gc0 = *reinterpret_cast<const s16x8*>(pcr);
        s16x8 gc1 = *reinterpret_cast<const s16x8*>(pcr + 8);

        // next-tile prefetch: idx + Ef
        const int en = tc * 32 + n;
        int i0n = __builtin_nontemporal_load(idx + en);
        int i1n = __builtin_nontemporal_load(idx + nE + en);
        const float* efpn = Ef + (size_t)en * 32 + 16 * g;
        f32x4 efn0 = __builtin_nontemporal_load(reinterpret_cast<const f32x4*>(efpn + 0));
        f32x4 efn1 = __builtin_nontemporal_load(reinterpret_cast<const f32x4*>(efpn + 4));
        f32x4 efn2 = __builtin_nontemporal_load(reinterpret_cast<const f32x4*>(efpn + 8));
        f32x4 efn3 = __builtin_nontemporal_load(reinterpret_cast<const f32x4*>(efpn + 12));

        // ---- layer 1: Ef part (regs already resident from prefetch) ----
        f32x16 acc = {};
        {
            s16x4 bE0 = pack4v(ef0), bE1 = pack4v(ef1), bE2 = pack4v(ef2), bE3 = pack4v(ef3);
            acc = __builtin_amdgcn_mfma_f32_32x32x8bf16_1k(aW1[0], bE0, acc, 0, 0, 0);
            acc = __builtin_amdgcn_mfma_f32_32x32x8bf16_1k(aW1[1], bE1, acc, 0, 0, 0);
            acc = __builtin_amdgcn_mfma_f32_32x32x8bf16_1k(aW1[2], bE2, acc, 0, 0, 0);
            acc = __builtin_amdgcn_mfma_f32_32x32x8bf16_1k(aW1[3], bE3, acc, 0, 0, 0);
        }
        // ---- layer 1: gathered node partials via identity MFMAs ----
        acc = __builtin_amdgcn_mfma_f32_32x32x8bf16_1k(aI[0], lo4(gv0), acc, 0, 0, 0);
        acc = __builtin_amdgcn_mfma_f32_32x32x8bf16_1k(aI[1], hi4(gv0), acc, 0, 0, 0);
        acc = __builtin_amdgcn_mfma_f32_32x32x8bf16_1k(aI[2], lo4(gv1), acc, 0, 0, 0);
        acc = __builtin_amdgcn_mfma_f32_32x32x8bf16_1k(aI[3], hi4(gv1), acc, 0, 0, 0);
        acc = __builtin_amdgcn_mfma_f32_32x32x8bf16_1k(aI[0], lo4(gc0), acc, 0, 0, 0);
        acc = __builtin_amdgcn_mfma_f32_32x32x8bf16_1k(aI[1], hi4(gc0), acc, 0, 0, 0);
        acc = __builtin_amdgcn_mfma_f32_32x32x8bf16_1k(aI[2], lo4(gc1), acc, 0, 0, 0);
        acc = __builtin_amdgcn_mfma_f32_32x32x8bf16_1k(aI[3], hi4(gc1), acc, 0, 0, 0);

        // relu + pack -> layer-2 B frags (D quads align with k-groups)
        s16x4 bH[4];
#pragma unroll
        for (int q = 0; q < 4; ++q)
            bH[q] = pack4(fmaxf(acc[4*q+0], 0.f), fmaxf(acc[4*q+1], 0.f),
                          fmaxf(acc[4*q+2], 0.f), fmaxf(acc[4*q+3], 0.f));

        f32x16 acc2 = {};
        acc2 = __builtin_amdgcn_mfma_f32_32x32x8bf16_1k(aB2, bOne, acc2, 0, 0, 0);
#pragma unroll
        for (int q = 0; q < 4; ++q)
            acc2 = __builtin_amdgcn_mfma_f32_32x32x8bf16_1k(aW2[q], bH[q], acc2, 0, 0, 0);

        // ---- store: wave-private LDS transpose (stride 34), then nt stores ----
        {
            float* orow = ldsw + n * 34;
#pragma unroll
            for (int q = 0; q < 4; ++q) {
                f32x2 lo; lo[0] = acc2[4*q+0]; lo[1] = acc2[4*q+1];
                f32x2 hi; hi[0] = acc2[4*q+2]; hi[1] = acc2[4*q+3];
                *reinterpret_cast<f32x2*>(orow + 8 * q + 4 * g)     = lo;
                *reinterpret_cast<f32x2*>(orow + 8 * q + 4 * g + 2) = hi;
            }
            float* obase = out + (size_t)t * 1024;
#pragma unroll
            for (int p = 0; p < 4; ++p) {
                int li = p * 256 + lane * 4;
                int row = li >> 5, col = li & 31;
                const float* s = ldsw + row * 34 + col;
                f32x2 lo = *reinterpret_cast<const f32x2*>(s);
                f32x2 hi = *reinterpret_cast<const f32x2*>(s + 2);
                f32x4 v; v[0] = lo[0]; v[1] = lo[1]; v[2] = hi[0]; v[3] = hi[1];
                __builtin_nontemporal_store(v, reinterpret_cast<f32x4*>(obase + li));
            }
        }

        if (tn >= ntile) break;
        t = tn;
        i0c = i0n; i1c = i1n;
        ef0 = efn0; ef1 = efn1; ef2 = efn2; ef3 = efn3;
    }
}

extern "C" void kernel_launch(void* const* d_in, const int* in_sizes, int n_in,
                              void* d_out, int out_size, void* d_ws, size_t ws_size,
                              hipStream_t stream) {
    const float* var_f = (const float*)d_in[0];
    const float* con_f = (const float*)d_in[1];
    const float* Ef    = (const float*)d_in[2];
    const int*   idx   = (const int*)d_in[3];
    const float* Wv1 = (const float*)d_in[4];
    const float* bv1 = (const float*)d_in[5];
    const float* Wv2 = (const float*)d_in[6];
    const float* bv2 = (const float*)d_in[7];
    const float* Wc1 = (const float*)d_in[8];
    const float* bc1 = (const float*)d_in[9];
    const float* Wc2 = (const float*)d_in[10];
    const float* bc2 = (const float*)d_in[11];
    const float* We1 = (const float*)d_in[12];
    const float* be1 = (const float*)d_in[13];
    const float* We2 = (const float*)d_in[14];
    const float* be2 = (const float*)d_in[15];
    float* out = (float*)d_out;

    const int nV = in_sizes[0] / 32;
    const int nC = in_sizes[1] / 32;
    const int nE = in_sizes[2] / 32;

    unsigned short* pv = (unsigned short*)d_ws;
    unsigned short* pc = pv + (size_t)nV * 32;

    const int blocksV = ((((nV + 31) >> 5) + 3) / 4);
    const int blocksC = ((((nC + 31) >> 5) + 3) / 4);
    nodes_kernel<<<blocksV + blocksC, 256, 0, stream>>>(
        var_f, con_f, Wv1, bv1, Wv2, bv2, Wc1, bc1, Wc2, bc2,
        We1, be1, pv, pc, nV, nC, blocksV);

    edge_kernel<<<1024, 256, 0, stream>>>(Ef, idx, pv, pc, We1, We2, be2, out, nE);
}